// Round 19
// baseline (1063.023 us; speedup 1.0000x reference)
//
#include <hip/hip_runtime.h>
#include <math.h>

#define NS   512   // states
#define NO   1024  // observations
#define NB   64    // batch
#define TMAX 512

// A stored fp8 e5m2 (x256 scale), k-split layout. Per-thread 32 uint4
// chunks (16 k-values each), chunk c8 = j*4+n: output 64j+l, k = 64w+16n..+15.
// c8 0..18 -> areg8 (76 VGPR -- fits the 128-reg budget, stream ~0);
// c8 19..31 -> LDS (13 chunks, 104 KB).
#define QREG8 19
#define QLDS8 13

typedef _Float16 h2v __attribute__((ext_vector_type(2)));

__device__ inline float wave_red_sum(float x) {
#pragma unroll
  for (int o = 32; o; o >>= 1) x += __shfl_xor(x, o, 64);
  return x;
}
__device__ inline float wave_red_max(float x) {
#pragma unroll
  for (int o = 32; o; o >>= 1) x = fmaxf(x, __shfl_xor(x, o, 64));
  return x;
}

__device__ inline float dot2u(unsigned int a, unsigned int b, float c) {
#if __has_builtin(__builtin_amdgcn_fdot2)
  return __builtin_amdgcn_fdot2(__builtin_bit_cast(h2v, a),
                                __builtin_bit_cast(h2v, b), c, false);
#else
  h2v av = __builtin_bit_cast(h2v, a), bv = __builtin_bit_cast(h2v, b);
  return c + (float)av.x * (float)bv.x + (float)av.y * (float)bv.y;
#endif
}

// e5m2 -> fp16 expansion: exact byte shift (same exponent width).
// lo: bytes 0,1 -> fp16 pair; hi: bytes 2,3.  (r15-validated)
__device__ inline unsigned int ex_lo(unsigned int w) {
#if __has_builtin(__builtin_amdgcn_perm)
  return __builtin_amdgcn_perm(0u, w, 0x010C000Cu);
#else
  return ((w & 0xFFu) << 8) | ((w & 0xFF00u) << 16);
#endif
}
__device__ inline unsigned int ex_hi(unsigned int w) {
#if __has_builtin(__builtin_amdgcn_perm)
  return __builtin_amdgcn_perm(0u, w, 0x030C020Cu);
#else
  return ((w & 0x00FF0000u) >> 8) | (w & 0xFF000000u);
#endif
}

// float -> e5m2 byte (RTNE via fp16 then round mantissa 10->2 bits).
__device__ inline unsigned int f2e5m2(float f) {
  unsigned short hb = __builtin_bit_cast(unsigned short, (_Float16)f);
  unsigned int r = (unsigned int)hb + 0x7Fu + ((hb >> 8) & 1u);
  return (r >> 8) & 0xFFu;
}

// P1: pi softmax -> pi_sm[512]
__global__ void k_pi(const float* __restrict__ pi, float* __restrict__ pi_sm) {
  __shared__ float red[8];
  int tid = threadIdx.x;
  float v = pi[tid];
  float m = wave_red_max(v);
  if ((tid & 63) == 0) red[tid >> 6] = m;
  __syncthreads();
  m = fmaxf(fmaxf(fmaxf(red[0], red[1]), fmaxf(red[2], red[3])),
            fmaxf(fmaxf(red[4], red[5]), fmaxf(red[6], red[7])));
  float e = __expf(v - m);
  float s = wave_red_sum(e);
  __syncthreads();
  if ((tid & 63) == 0) red[tid >> 6] = s;
  __syncthreads();
  s = red[0] + red[1] + red[2] + red[3] + red[4] + red[5] + red[6] + red[7];
  pi_sm[tid] = e / s;
}

// P2: column logsumexp of A (axis 0). One block (256 thr) per column. grid 512.
__global__ void k_colLse(const float* __restrict__ A, float* __restrict__ lseA) {
  __shared__ float redm[4];
  __shared__ float reds[4];
  int k = blockIdx.x, tid = threadIdx.x;
  float a0 = A[tid * NS + k], a1 = A[(tid + 256) * NS + k];
  float m = wave_red_max(fmaxf(a0, a1));
  if ((tid & 63) == 0) redm[tid >> 6] = m;
  __syncthreads();
  m = fmaxf(fmaxf(redm[0], redm[1]), fmaxf(redm[2], redm[3]));
  float s = __expf(a0 - m) + __expf(a1 - m);
  s = wave_red_sum(s);
  if ((tid & 63) == 0) reds[tid >> 6] = s;
  __syncthreads();
  s = reds[0] + reds[1] + reds[2] + reds[3];
  if (tid == 0) lseA[k] = m + __logf(s);
}

// P3: row logsumexp of E (axis 1). One block per row. grid 512 x 256.
__global__ void k_rowLseE(const float* __restrict__ E, float* __restrict__ lseE) {
  __shared__ float red[4];
  int i = blockIdx.x, tid = threadIdx.x;
  const float* row = E + i * NO;
  float a0 = row[tid], a1 = row[tid + 256], a2 = row[tid + 512], a3 = row[tid + 768];
  float m = fmaxf(fmaxf(a0, a1), fmaxf(a2, a3));
  m = wave_red_max(m);
  if ((tid & 63) == 0) red[tid >> 6] = m;
  __syncthreads();
  m = fmaxf(fmaxf(red[0], red[1]), fmaxf(red[2], red[3]));
  float s = __expf(a0 - m) + __expf(a1 - m) + __expf(a2 - m) + __expf(a3 - m);
  s = wave_red_sum(s);
  __syncthreads();
  if ((tid & 63) == 0) red[tid >> 6] = s;
  __syncthreads();
  s = red[0] + red[1] + red[2] + red[3];
  if (tid == 0) lseE[i] = m + __logf(s);
}

// P4: pack A_exp8 = e5m2(exp(A - lseA[col]) * 256) for the k-split layout.
// k_fwd thread t (w=t>>6, l=t&63), chunk c8 = j*4+n: uint4 Apk[c8*512+t]
// = output 64j+l, k = 64w+16n..+15. Word u = (c8*512+t)*4 + h packs bytes
// k = 64w+16n+4h+{0,1,2,3}. grid 128 x 512.
__global__ void k_pack(const float* __restrict__ A, const float* __restrict__ lseA,
                       unsigned int* __restrict__ W) {
  int u = blockIdx.x * 512 + threadIdx.x;   // [0, 65536)
  int h = u & 3;
  int ct = u >> 2;
  int t = ct & 511;
  int c8 = ct >> 9;
  int j = c8 >> 2, n = c8 & 3;
  int w = t >> 6, l = t & 63;
  int i  = 64 * j + l;
  int k0 = 64 * w + 16 * n + 4 * h;
  const float* row = A + i * NS;
  unsigned int b0 = f2e5m2(__expf(row[k0]     - lseA[k0])     * 256.f);
  unsigned int b1 = f2e5m2(__expf(row[k0 + 1] - lseA[k0 + 1]) * 256.f);
  unsigned int b2 = f2e5m2(__expf(row[k0 + 2] - lseA[k0 + 2]) * 256.f);
  unsigned int b3 = f2e5m2(__expf(row[k0 + 3] - lseA[k0 + 3]) * 256.f);
  W[u] = b0 | (b1 << 8) | (b2 << 16) | (b3 << 24);
}

// Main forward: one block (512 thr, 8 waves) per batch; 8-way k-split,
// ONE barrier per step (r17-proven schedule: wave w's u-slice is written
// by its own lanes -> no barrier on u; Pf ping-pong kills the WAR; red[]
// deferred one barrier).
// A in fp8 e5m2 x256 (r15-validated numerics, absmax 16 << 70.7): per-thread
// 19 uint4 in regs + 13 in LDS -> the 250 KB/step L2 stream (r17's measured
// critical path at ~71 B/cy) drops to ~0. VALU doubles (256 perm + 256
// fdot2) but was idle 70% in r17. Deferred pow2 rescale throughout.
// [resubmit: r18 was a broker-level container failure, not source]
__global__ __launch_bounds__(512, 1) void k_fwd(
    const float* __restrict__ E, const int* __restrict__ x,
    const int* __restrict__ Tlen, const float* __restrict__ pi_sm,
    const float* __restrict__ lseE, const uint4* __restrict__ Apk,
    float* __restrict__ out) {
  __shared__ uint4 Alds[QLDS8 * 512];           // 104 KB
  __shared__ float Pf[2][8 * 512];              // 32 KB ping-pong partials
  __shared__ uint4 ubuf[NS / 8];                // 1 KB u (fp16), single buffer
  __shared__ int xrow[TMAX];                    // 2 KB
  __shared__ __align__(16) float red[2][8];     // ping-pong sigma partials
  int b = blockIdx.x, tid = threadIdx.x;
  int w = tid >> 6, l = tid & 63;

  // Prologue: chunks 0..18 -> areg8 (fits regs), 19..31 -> LDS.
  uint4 areg8[QREG8];
#pragma unroll
  for (int q = 0; q < QREG8; q++) areg8[q] = Apk[q * 512 + tid];
#pragma unroll
  for (int q = 0; q < QLDS8; q++) Alds[q * 512 + tid] = Apk[(QREG8 + q) * 512 + tid];

  for (int t2 = tid; t2 < TMAX; t2 += 512) xrow[t2] = x[b * TMAX + t2];

  float pi_i  = pi_sm[tid];
  float lse_i = lseE[tid];
  const float* Erow = E + tid * NO;
  int Tb = Tlen[b];
  float c = 0.f;        // log2-domain accumulator
  float Dlog = 0.f;     // log2 d_{t-1}
  int gexp_prev = 19;
  int cur = 0;          // parity for Pf and red
  __syncthreads();

  for (int t = 0; t < Tb; t++) {
    int nxt = cur ^ 1;
    float epre = Erow[xrow[t]];     // issued early; latency hides under dot
    if (t) {
      // wave's 8 uniform u-chunks (k-slice [64w, 64w+64)), own-wave written
      uint4 uvA0 = ubuf[8 * w + 0], uvB0 = ubuf[8 * w + 1];
      uint4 uvA1 = ubuf[8 * w + 2], uvB1 = ubuf[8 * w + 3];
      uint4 uvA2 = ubuf[8 * w + 4], uvB2 = ubuf[8 * w + 5];
      uint4 uvA3 = ubuf[8 * w + 6], uvB3 = ubuf[8 * w + 7];
      float acc[8];
#pragma unroll
      for (int j = 0; j < 8; j++) acc[j] = 0.f;
#pragma unroll
      for (int j = 0; j < 8; j++) {
#pragma unroll
        for (int n = 0; n < 4; n++) {
          int c8 = j * 4 + n;   // compile-time constant (full unroll)
          uint4 av = (c8 < QREG8) ? areg8[c8] : Alds[(c8 - QREG8) * 512 + tid];
          uint4 uvA = (n == 0) ? uvA0 : (n == 1) ? uvA1 : (n == 2) ? uvA2 : uvA3;
          uint4 uvB = (n == 0) ? uvB0 : (n == 1) ? uvB1 : (n == 2) ? uvB2 : uvB3;
          acc[j] = dot2u(ex_lo(av.x), uvA.x, acc[j]);
          acc[j] = dot2u(ex_hi(av.x), uvA.y, acc[j]);
          acc[j] = dot2u(ex_lo(av.y), uvA.z, acc[j]);
          acc[j] = dot2u(ex_hi(av.y), uvA.w, acc[j]);
          acc[j] = dot2u(ex_lo(av.z), uvB.x, acc[j]);
          acc[j] = dot2u(ex_hi(av.z), uvB.y, acc[j]);
          acc[j] = dot2u(ex_lo(av.w), uvB.z, acc[j]);
          acc[j] = dot2u(ex_hi(av.w), uvB.w, acc[j]);
        }
      }
      // partials: Pf[cur][w][64j + l] -- lanes consecutive, conflict-free
#pragma unroll
      for (int j = 0; j < 8; j++) Pf[cur][w * 512 + j * 64 + l] = acc[j];
    }
    __syncthreads();   // THE barrier: Pf(cur) + red(cur) visible

    // Owner phase: thread tid owns state i = tid (= 64w + l, own wave).
    {
      int gexpw = 19;
      if (t) {
        // consume sigma of step t-1 (written at owner(t-1), 1 barrier ago)
        const float4* rp = (const float4*)red[cur];
        float4 ra = rp[0], rb = rp[1];
        float sp = ((ra.x + ra.y) + (ra.z + ra.w)) + ((rb.x + rb.y) + (rb.z + rb.w));
        float ls = __log2f(sp);
        int e = ((__builtin_bit_cast(int, sp) >> 23) & 0xff) - 126;  // sp=m*2^e
        c += ls - Dlog;
        Dlog = (float)gexp_prev + ls;
        gexpw = 19 - gexp_prev - e;
      }
      float em = __expf(epre - lse_i);
      float raw;
      if (t) {
        const float* pf = Pf[cur];
        float s0 = pf[tid]          + pf[512 + tid];
        float s1 = pf[1024 + tid]   + pf[1536 + tid];
        float s2 = pf[2048 + tid]   + pf[2560 + tid];
        float s3 = pf[3072 + tid]   + pf[3584 + tid];
        // undo the x256 A-scale (exact pow2) folded into one multiply
        raw = ((s0 + s1) + (s2 + s3)) * (em * 0.00390625f);
      } else {
        raw = pi_i * em;
      }
      // u[tid]: consumed only by this wave's dot(t+1) -- no barrier needed
      ((_Float16*)ubuf)[tid] = (_Float16)ldexpf(raw, gexpw);
      // sigma partial for step t, consumed at owner(t+1) after next barrier
      float s = wave_red_sum(raw);
      if (l == 0) red[nxt][w] = s;
      gexp_prev = gexpw;
    }
    cur = nxt;
  }
  // final: consume last step's sigma (written at owner(Tb-1) to red[cur])
  __syncthreads();
  {
    const float4* rp = (const float4*)red[cur];
    float4 ra = rp[0], rb = rp[1];
    float sp = ((ra.x + ra.y) + (ra.z + ra.w)) + ((rb.x + rb.y) + (rb.z + rb.w));
    c += __log2f(sp) - Dlog;
  }
  if (tid == 0) out[b] = c * 0.69314718055994530942f;
}

extern "C" void kernel_launch(void* const* d_in, const int* in_sizes, int n_in,
                              void* d_out, int out_size, void* d_ws, size_t ws_size,
                              hipStream_t stream) {
  const float* pi = (const float*)d_in[0];
  const float* A  = (const float*)d_in[1];
  const float* E  = (const float*)d_in[2];
  const int*   x  = (const int*)d_in[3];
  const int*   T  = (const int*)d_in[4];
  float* out = (float*)d_out;

  char* ws = (char*)d_ws;
  float*        pi_sm = (float*)(ws + 0);
  float*        lseA  = (float*)(ws + 2048);
  float*        lseE  = (float*)(ws + 4096);
  unsigned int* Apk   = (unsigned int*)(ws + 6144);  // 512*512 fp8 = 256 KB

  hipLaunchKernelGGL(k_pi,      dim3(1),   dim3(512), 0, stream, pi, pi_sm);
  hipLaunchKernelGGL(k_colLse,  dim3(512), dim3(256), 0, stream, A, lseA);
  hipLaunchKernelGGL(k_rowLseE, dim3(512), dim3(256), 0, stream, E, lseE);
  hipLaunchKernelGGL(k_pack,    dim3(128), dim3(512), 0, stream, A, lseA, Apk);
  hipLaunchKernelGGL(k_fwd,     dim3(64),  dim3(512), 0, stream,
                     E, x, T, pi_sm, lseE, (const uint4*)Apk, out);
}